// Round 7
// baseline (184.040 us; speedup 1.0000x reference)
//
#include <hip/hip_runtime.h>
#include <math.h>

// labels = argmin_k ||c1_k||^2 - 2*x.c1_k, x = inpt[:,64:128] (131072x64),
// centers1 (1024x64). centers0 unused. Output int32 labels.
constexpr int N_ROWS   = 131072;
constexpr int INPT_DIM = 128;
constexpr int DIM      = 64;
constexpr int COL_OFF  = 64;
constexpr int NCENT    = 1024;

constexpr int TM    = 64;           // rows per block
constexpr int NTILE = NCENT / 16;   // 64 tiles of 16 centers
constexpr int TPW   = NTILE / 4;    // 16 tiles per wave
constexpr int MAXC  = 16;           // candidates/row (E~1.5 under final thresh)

typedef short short8 __attribute__((ext_vector_type(8)));
typedef float f32x4  __attribute__((ext_vector_type(4)));

// ws: [0,8192) f64 cnorm | [8192,12288) f32 cnorm | [12288,12292) maxC bits
//     [16384, 16384+131072) bf16 centers, MFMA-fragment-linear:
//     frag (tile t, khalf f) lane l: 8 bf16 at ((t*2+f)*64 + l)*8
//     = centers[t*16 + (l&15)][f*32 + (l>>4)*8 + j]   (B[n][k], m89 layout)

__device__ __forceinline__ unsigned short f2bf(float f) {
    unsigned u = __float_as_uint(f);
    u += 0x7fff + ((u >> 16) & 1);          // round-to-nearest-even
    return (unsigned short)(u >> 16);
}

__device__ __forceinline__ double exact_score(const float* __restrict__ c,
                                              const float* __restrict__ x, double cn) {
    double acc = 0.0;
#pragma unroll
    for (int d = 0; d < DIM; ++d)
        acc = fma((double)c[d], (double)x[d], acc);
    return fma(-2.0, acc, cn);
}

// ---------------------------------------------------------------------------
// Prep (R6 v2, unchanged): 4 threads/center, coalesced 64B quarter-rows.
// ---------------------------------------------------------------------------
__global__ __launch_bounds__(256) void prep_kernel(const float* __restrict__ centers,
                                                   double* __restrict__ cnorm_d,
                                                   float* __restrict__ cnorm_f,
                                                   int* __restrict__ maxc_i,
                                                   unsigned short* __restrict__ cbf) {
    int tid = blockIdx.x * 256 + threadIdx.x;   // 0..4095
    int k = tid >> 2, kq = tid & 3;
    const float* c = centers + (size_t)k * DIM + kq * 16;
    float cf[16];
    double sd = 0.0;
#pragma unroll
    for (int j = 0; j < 4; ++j) {
        float4 v = *reinterpret_cast<const float4*>(c + j * 4);
        cf[j * 4] = v.x; cf[j * 4 + 1] = v.y; cf[j * 4 + 2] = v.z; cf[j * 4 + 3] = v.w;
        sd = fma((double)v.x, (double)v.x, sd);
        sd = fma((double)v.y, (double)v.y, sd);
        sd = fma((double)v.z, (double)v.z, sd);
        sd = fma((double)v.w, (double)v.w, sd);
    }
    sd += __shfl_xor(sd, 1);
    sd += __shfl_xor(sd, 2);
    if (kq == 0) { cnorm_d[k] = sd; cnorm_f[k] = (float)sd; }

    int t = k >> 4, n = k & 15, f = kq >> 1;
#pragma unroll
    for (int h = 0; h < 2; ++h) {
        int qq = (kq & 1) * 2 + h;
        const float* s = cf + h * 8;
        uint4 w;
        w.x = (unsigned)f2bf(s[0]) | ((unsigned)f2bf(s[1]) << 16);
        w.y = (unsigned)f2bf(s[2]) | ((unsigned)f2bf(s[3]) << 16);
        w.z = (unsigned)f2bf(s[4]) | ((unsigned)f2bf(s[5]) << 16);
        w.w = (unsigned)f2bf(s[6]) | ((unsigned)f2bf(s[7]) << 16);
        *reinterpret_cast<uint4*>(cbf + ((size_t)((t * 2 + f) * 64 + qq * 16 + n)) * 8) = w;
    }
    float nm = sqrtf((float)sd);
#pragma unroll
    for (int mk = 1; mk < 64; mk <<= 1)
        nm = fmaxf(nm, __shfl_xor(nm, mk));
    if ((threadIdx.x & 63) == 0) atomicMax(maxc_i, __float_as_int(nm));  // poison<0 loses
}

// ---------------------------------------------------------------------------
// Main: 4 waves/block, 64 rows, centers split by wave (wave w: tiles
// [16w,16w+16)). R6 post-mortem: 1 wave/block = 2 waves/SIMD; ~12x issue-floor
// gap, all exposed L2 latency; compiler discards manual double-buffering
// (VGPR=84). Fix = TLP: 4 waves/block -> up to 20+ waves/CU; per-wave serial
// chain /4; B traffic unchanged (each tile owned by one wave).
// Pass-1 partial mins combine via wavemin[64][4] LDS (+1 barrier); thresholds
// use the true global bf16 min => superset/exactness argument unchanged.
// ---------------------------------------------------------------------------
__global__ __launch_bounds__(256, 4) void label_kernel(
        const float* __restrict__ inpt, const float* __restrict__ centers,
        const double* __restrict__ cnorm_d, const float* __restrict__ cnorm_f,
        const int* __restrict__ maxc_i, const unsigned short* __restrict__ cbf,
        int* __restrict__ out) {
    __shared__ unsigned short A_lds[TM][72];   // 144B rows: frag reads 2-way (free)
    __shared__ float cn_lds[NCENT];
    __shared__ float margin_lds[TM];
    __shared__ float nx2p[TM][4];
    __shared__ float wavemin[TM][4];           // [row][wave] -> float4 reads
    __shared__ int   cand[TM][MAXC];
    __shared__ int   ccount[TM];

    const int tid  = threadIdx.x;
    const int lane = tid & 63;
    const int w    = tid >> 6;                 // wave id 0..3
    const int rowBase = blockIdx.x * TM;

    // ---- stage: thread (r,kq) converts 16 dims of row r; nx2 via partials
    {
        int r = tid >> 2, kq = tid & 3;
        const float* xp = inpt + (size_t)(rowBase + r) * INPT_DIM + COL_OFF + kq * 16;
        float ss = 0.f;
#pragma unroll
        for (int j = 0; j < 4; ++j) {
            float4 v = *reinterpret_cast<const float4*>(xp + j * 4);
            ss = fmaf(v.x, v.x, fmaf(v.y, v.y, fmaf(v.z, v.z, fmaf(v.w, v.w, ss))));
            unsigned u0 = (unsigned)f2bf(v.x) | ((unsigned)f2bf(v.y) << 16);
            unsigned u1 = (unsigned)f2bf(v.z) | ((unsigned)f2bf(v.w) << 16);
            *reinterpret_cast<unsigned*>(&A_lds[r][kq * 16 + j * 4])     = u0;
            *reinterpret_cast<unsigned*>(&A_lds[r][kq * 16 + j * 4 + 2]) = u1;
        }
        nx2p[r][kq] = ss;
        // cn_lds: 256 threads x float4
        *reinterpret_cast<float4*>(&cn_lds[tid * 4]) =
            *reinterpret_cast<const float4*>(cnorm_f + tid * 4);
    }
    __syncthreads();
    if (tid < TM) {
        float nx2 = nx2p[tid][0] + nx2p[tid][1] + nx2p[tid][2] + nx2p[tid][3];
        // bf16 score err <= 2^-7|x||c| each way; formula unchanged since R3 (absmax=0)
        margin_lds[tid] = (1.5f / 64.f) * sqrtf(nx2) * __int_as_float(maxc_i[0]) + 1e-3f;
        ccount[tid] = 0;
    }
    __syncthreads();

    const int m = lane & 15, q = lane >> 4;
    short8 af0[4], af1[4];   // m89: A[m=lane&15][k=q*8+j]; 4 sets of 16 rows
#pragma unroll
    for (int s = 0; s < 4; ++s) {
        af0[s] = *reinterpret_cast<const short8*>(&A_lds[s * 16 + m][q * 8]);
        af1[s] = *reinterpret_cast<const short8*>(&A_lds[s * 16 + m][32 + q * 8]);
    }

    const short8* bfrag = reinterpret_cast<const short8*>(cbf);
    const int tBase = w * TPW;

    // ================= pass 1: running min over this wave's 256 centers ======
    float rmin[4][4];
#pragma unroll
    for (int s = 0; s < 4; ++s)
#pragma unroll
        for (int r4 = 0; r4 < 4; ++r4) rmin[s][r4] = INFINITY;

#pragma unroll 4
    for (int i = 0; i < TPW; ++i) {
        int t = tBase + i;
        short8 b0 = bfrag[(t * 2 + 0) * 64 + lane];
        short8 b1 = bfrag[(t * 2 + 1) * 64 + lane];
        float cn = cn_lds[t * 16 + m];
#pragma unroll
        for (int s = 0; s < 4; ++s) {
            f32x4 acc = {0.f, 0.f, 0.f, 0.f};
            acc = __builtin_amdgcn_mfma_f32_16x16x32_bf16(af0[s], b0, acc, 0, 0, 0);
            acc = __builtin_amdgcn_mfma_f32_16x16x32_bf16(af1[s], b1, acc, 0, 0, 0);
#pragma unroll
            for (int r4 = 0; r4 < 4; ++r4)   // D: col=m (center), row=q*4+r4
                rmin[s][r4] = fminf(rmin[s][r4], fmaf(-2.f, acc[r4], cn));
        }
    }

    // in-wave reduction over the 16-lane m-groups, then publish per-wave mins
#pragma unroll
    for (int s = 0; s < 4; ++s) {
#pragma unroll
        for (int r4 = 0; r4 < 4; ++r4) {
            float v = rmin[s][r4];
            v = fminf(v, __shfl_xor(v, 1));
            v = fminf(v, __shfl_xor(v, 2));
            v = fminf(v, __shfl_xor(v, 4));
            v = fminf(v, __shfl_xor(v, 8));
            if (m == 0) wavemin[s * 16 + q * 4 + r4][w] = v;
        }
    }
    __syncthreads();

    // global per-row thresholds = min over 4 waves + margin
    float thresh[4][4], tmax[4];
    float tmax_all = -INFINITY;
#pragma unroll
    for (int s = 0; s < 4; ++s) {
        tmax[s] = -INFINITY;
#pragma unroll
        for (int r4 = 0; r4 < 4; ++r4) {
            int row = s * 16 + q * 4 + r4;
            float4 wm = *reinterpret_cast<const float4*>(&wavemin[row][0]);
            float v = fminf(fminf(wm.x, wm.y), fminf(wm.z, wm.w)) + margin_lds[row];
            thresh[s][r4] = v;
            tmax[s] = fmaxf(tmax[s], v);
        }
        tmax_all = fmaxf(tmax_all, tmax[s]);
    }

    // ================= pass 2: rescan own tiles, append candidates ===========
#pragma unroll 2
    for (int i = 0; i < TPW; ++i) {
        int t = tBase + i;
        short8 b0 = bfrag[(t * 2 + 0) * 64 + lane];
        short8 b1 = bfrag[(t * 2 + 1) * 64 + lane];
        float cn = cn_lds[t * 16 + m];
        f32x4 sc[4];
        float cmin = INFINITY;
#pragma unroll
        for (int s = 0; s < 4; ++s) {
            f32x4 acc = {0.f, 0.f, 0.f, 0.f};
            acc = __builtin_amdgcn_mfma_f32_16x16x32_bf16(af0[s], b0, acc, 0, 0, 0);
            acc = __builtin_amdgcn_mfma_f32_16x16x32_bf16(af1[s], b1, acc, 0, 0, 0);
#pragma unroll
            for (int r4 = 0; r4 < 4; ++r4) {
                sc[s][r4] = fmaf(-2.f, acc[r4], cn);
                cmin = fminf(cmin, sc[s][r4]);
            }
        }
        if (cmin < tmax_all) {            // rare: detailed per-row checks
#pragma unroll
            for (int s = 0; s < 4; ++s) {
                float smin = fminf(fminf(sc[s][0], sc[s][1]), fminf(sc[s][2], sc[s][3]));
                if (smin < tmax[s]) {
#pragma unroll
                    for (int r4 = 0; r4 < 4; ++r4) {
                        if (sc[s][r4] < thresh[s][r4]) {   // pass1==pass2 scores
                            int row = s * 16 + q * 4 + r4;
                            int slot = atomicAdd(&ccount[row], 1);
                            if (slot < MAXC) cand[row][slot] = t * 16 + m;
                        }
                    }
                }
            }
        }
    }
    __syncthreads();

    // ---- exact f64 resolve: tid<64 resolves row tid (argmin guaranteed in list)
    if (tid < TM) {
        int cnt = ccount[tid];
        int best;
        if (cnt == 1) {
            best = cand[tid][0];
        } else {
            const float* xp = inpt + (size_t)(rowBase + tid) * INPT_DIM + COL_OFF;
            double bestv = 1e300;
            best = 0x7fffffff;
            if (cnt <= MAXC) {
                for (int j = 0; j < cnt; ++j) {
                    int k = cand[tid][j];
                    double s = exact_score(centers + (size_t)k * DIM, xp, cnorm_d[k]);
                    if (s < bestv || (s == bestv && k < best)) { bestv = s; best = k; }
                }
            } else {  // overflow fallback: full exact scan (P ~ 0)
                for (int k = 0; k < NCENT; ++k) {
                    double s = exact_score(centers + (size_t)k * DIM, xp, cnorm_d[k]);
                    if (s < bestv) { bestv = s; best = k; }
                }
            }
        }
        out[rowBase + tid] = best;
    }
}

// ---------------------------------------------------------------------------
extern "C" void kernel_launch(void* const* d_in, const int* in_sizes, int n_in,
                              void* d_out, int out_size, void* d_ws, size_t ws_size,
                              hipStream_t stream) {
    const float* inpt     = (const float*)d_in[0];
    const float* centers1 = (const float*)d_in[2];   // centers0 (d_in[1]) unused
    int* out = (int*)d_out;

    char* ws = (char*)d_ws;
    double* cnorm_d = (double*)ws;
    float*  cnorm_f = (float*)(ws + 8192);
    int*    maxc_i  = (int*)(ws + 12288);
    unsigned short* cbf = (unsigned short*)(ws + 16384);

    prep_kernel<<<16, 256, 0, stream>>>(centers1, cnorm_d, cnorm_f, maxc_i, cbf);
    label_kernel<<<N_ROWS / TM, 256, 0, stream>>>(inpt, centers1, cnorm_d, cnorm_f,
                                                  maxc_i, cbf, out);
}

// Round 8
// 180.360 us; speedup vs baseline: 1.0204x; 1.0204x over previous
//
#include <hip/hip_runtime.h>
#include <math.h>

// labels = argmin_k ||c1_k||^2 - 2*x.c1_k, x = inpt[:,64:128] (131072x64),
// centers1 (1024x64). centers0 unused. Output int32 labels.
constexpr int N_ROWS   = 131072;
constexpr int INPT_DIM = 128;
constexpr int DIM      = 64;
constexpr int COL_OFF  = 64;
constexpr int NCENT    = 1024;

constexpr int TM    = 64;           // rows per block
constexpr int NTILE = NCENT / 16;   // 64 tiles of 16 centers
constexpr int TPW   = NTILE / 4;    // 16 tiles per wave
constexpr int MAXC  = 16;           // candidates/row (E~1.5 under final thresh)

typedef short short8 __attribute__((ext_vector_type(8)));
typedef float f32x4  __attribute__((ext_vector_type(4)));

// ws: [0,8192) f64 cnorm | [8192,12288) f32 cnorm | [12288,12292) maxC bits
//     [16384, 16384+131072) bf16 centers, MFMA-fragment-linear:
//     frag (tile t, khalf f) lane l: 8 bf16 at ((t*2+f)*64 + l)*8
//     = centers[t*16 + (l&15)][f*32 + (l>>4)*8 + j]   (B[n][k], m89 layout)

__device__ __forceinline__ unsigned short f2bf(float f) {
    unsigned u = __float_as_uint(f);
    u += 0x7fff + ((u >> 16) & 1);          // round-to-nearest-even
    return (unsigned short)(u >> 16);
}

__device__ __forceinline__ double exact_score(const float* __restrict__ c,
                                              const float* __restrict__ x, double cn) {
    double acc = 0.0;
#pragma unroll
    for (int d = 0; d < DIM; ++d)
        acc = fma((double)c[d], (double)x[d], acc);
    return fma(-2.0, acc, cn);
}

// ---------------------------------------------------------------------------
// Prep (unchanged): 4 threads/center, coalesced 64B quarter-rows.
// ---------------------------------------------------------------------------
__global__ __launch_bounds__(256) void prep_kernel(const float* __restrict__ centers,
                                                   double* __restrict__ cnorm_d,
                                                   float* __restrict__ cnorm_f,
                                                   int* __restrict__ maxc_i,
                                                   unsigned short* __restrict__ cbf) {
    int tid = blockIdx.x * 256 + threadIdx.x;   // 0..4095
    int k = tid >> 2, kq = tid & 3;
    const float* c = centers + (size_t)k * DIM + kq * 16;
    float cf[16];
    double sd = 0.0;
#pragma unroll
    for (int j = 0; j < 4; ++j) {
        float4 v = *reinterpret_cast<const float4*>(c + j * 4);
        cf[j * 4] = v.x; cf[j * 4 + 1] = v.y; cf[j * 4 + 2] = v.z; cf[j * 4 + 3] = v.w;
        sd = fma((double)v.x, (double)v.x, sd);
        sd = fma((double)v.y, (double)v.y, sd);
        sd = fma((double)v.z, (double)v.z, sd);
        sd = fma((double)v.w, (double)v.w, sd);
    }
    sd += __shfl_xor(sd, 1);
    sd += __shfl_xor(sd, 2);
    if (kq == 0) { cnorm_d[k] = sd; cnorm_f[k] = (float)sd; }

    int t = k >> 4, n = k & 15, f = kq >> 1;
#pragma unroll
    for (int h = 0; h < 2; ++h) {
        int qq = (kq & 1) * 2 + h;
        const float* s = cf + h * 8;
        uint4 w;
        w.x = (unsigned)f2bf(s[0]) | ((unsigned)f2bf(s[1]) << 16);
        w.y = (unsigned)f2bf(s[2]) | ((unsigned)f2bf(s[3]) << 16);
        w.z = (unsigned)f2bf(s[4]) | ((unsigned)f2bf(s[5]) << 16);
        w.w = (unsigned)f2bf(s[6]) | ((unsigned)f2bf(s[7]) << 16);
        *reinterpret_cast<uint4*>(cbf + ((size_t)((t * 2 + f) * 64 + qq * 16 + n)) * 8) = w;
    }
    float nm = sqrtf((float)sd);
#pragma unroll
    for (int mk = 1; mk < 64; mk <<= 1)
        nm = fmaxf(nm, __shfl_xor(nm, mk));
    if ((threadIdx.x & 63) == 0) atomicMax(maxc_i, __float_as_int(nm));  // poison<0 loses
}

// ---------------------------------------------------------------------------
// Main: 4 waves/block, 64 rows, centers split by wave (wave w: tiles
// [16w,16w+16)). R7 post-mortem: launch_bounds(256,4) only FLOORS occupancy;
// backend chose 8 waves/EU @ 64 VGPR + 17 MB scratch spills (WRITE_SIZE).
// amdgpu_waves_per_eu(4,4) PINS the window: 128-VGPR cap, no incentive to
// squeeze; per-wave demand ~90 (R6's unconstrained build) fits spill-free.
// ---------------------------------------------------------------------------
__global__ __launch_bounds__(256)
__attribute__((amdgpu_waves_per_eu(4, 4)))
void label_kernel(
        const float* __restrict__ inpt, const float* __restrict__ centers,
        const double* __restrict__ cnorm_d, const float* __restrict__ cnorm_f,
        const int* __restrict__ maxc_i, const unsigned short* __restrict__ cbf,
        int* __restrict__ out) {
    __shared__ unsigned short A_lds[TM][72];   // 144B rows: frag reads 2-way (free)
    __shared__ float cn_lds[NCENT];
    __shared__ float margin_lds[TM];
    __shared__ float nx2p[TM][4];
    __shared__ float wavemin[TM][4];           // [row][wave] -> float4 reads
    __shared__ int   cand[TM][MAXC];
    __shared__ int   ccount[TM];

    const int tid  = threadIdx.x;
    const int lane = tid & 63;
    const int w    = tid >> 6;                 // wave id 0..3
    const int rowBase = blockIdx.x * TM;

    // ---- stage: thread (r,kq) converts 16 dims of row r; nx2 via partials
    {
        int r = tid >> 2, kq = tid & 3;
        const float* xp = inpt + (size_t)(rowBase + r) * INPT_DIM + COL_OFF + kq * 16;
        float ss = 0.f;
#pragma unroll
        for (int j = 0; j < 4; ++j) {
            float4 v = *reinterpret_cast<const float4*>(xp + j * 4);
            ss = fmaf(v.x, v.x, fmaf(v.y, v.y, fmaf(v.z, v.z, fmaf(v.w, v.w, ss))));
            unsigned u0 = (unsigned)f2bf(v.x) | ((unsigned)f2bf(v.y) << 16);
            unsigned u1 = (unsigned)f2bf(v.z) | ((unsigned)f2bf(v.w) << 16);
            *reinterpret_cast<unsigned*>(&A_lds[r][kq * 16 + j * 4])     = u0;
            *reinterpret_cast<unsigned*>(&A_lds[r][kq * 16 + j * 4 + 2]) = u1;
        }
        nx2p[r][kq] = ss;
        // cn_lds: 256 threads x float4
        *reinterpret_cast<float4*>(&cn_lds[tid * 4]) =
            *reinterpret_cast<const float4*>(cnorm_f + tid * 4);
    }
    __syncthreads();
    if (tid < TM) {
        float nx2 = nx2p[tid][0] + nx2p[tid][1] + nx2p[tid][2] + nx2p[tid][3];
        // bf16 score err <= 2^-7|x||c| each way; formula unchanged since R3 (absmax=0)
        margin_lds[tid] = (1.5f / 64.f) * sqrtf(nx2) * __int_as_float(maxc_i[0]) + 1e-3f;
        ccount[tid] = 0;
    }
    __syncthreads();

    const int m = lane & 15, q = lane >> 4;
    short8 af0[4], af1[4];   // m89: A[m=lane&15][k=q*8+j]; 4 sets of 16 rows
#pragma unroll
    for (int s = 0; s < 4; ++s) {
        af0[s] = *reinterpret_cast<const short8*>(&A_lds[s * 16 + m][q * 8]);
        af1[s] = *reinterpret_cast<const short8*>(&A_lds[s * 16 + m][32 + q * 8]);
    }

    const short8* bfrag = reinterpret_cast<const short8*>(cbf);
    const int tBase = w * TPW;

    // ================= pass 1: running min over this wave's 256 centers ======
    float rmin[4][4];
#pragma unroll
    for (int s = 0; s < 4; ++s)
#pragma unroll
        for (int r4 = 0; r4 < 4; ++r4) rmin[s][r4] = INFINITY;

#pragma unroll 2
    for (int i = 0; i < TPW; ++i) {            // unroll 2: <=2 tiles of B in flight
        int t = tBase + i;
        short8 b0 = bfrag[(t * 2 + 0) * 64 + lane];
        short8 b1 = bfrag[(t * 2 + 1) * 64 + lane];
        float cn = cn_lds[t * 16 + m];
#pragma unroll
        for (int s = 0; s < 4; ++s) {
            f32x4 acc = {0.f, 0.f, 0.f, 0.f};
            acc = __builtin_amdgcn_mfma_f32_16x16x32_bf16(af0[s], b0, acc, 0, 0, 0);
            acc = __builtin_amdgcn_mfma_f32_16x16x32_bf16(af1[s], b1, acc, 0, 0, 0);
#pragma unroll
            for (int r4 = 0; r4 < 4; ++r4)   // D: col=m (center), row=q*4+r4
                rmin[s][r4] = fminf(rmin[s][r4], fmaf(-2.f, acc[r4], cn));
        }
    }

    // in-wave reduction over the 16-lane m-groups, then publish per-wave mins
#pragma unroll
    for (int s = 0; s < 4; ++s) {
#pragma unroll
        for (int r4 = 0; r4 < 4; ++r4) {
            float v = rmin[s][r4];
            v = fminf(v, __shfl_xor(v, 1));
            v = fminf(v, __shfl_xor(v, 2));
            v = fminf(v, __shfl_xor(v, 4));
            v = fminf(v, __shfl_xor(v, 8));
            if (m == 0) wavemin[s * 16 + q * 4 + r4][w] = v;
        }
    }
    __syncthreads();

    // global per-row thresholds = min over 4 waves + margin
    float thresh[4][4], tmax[4];
    float tmax_all = -INFINITY;
#pragma unroll
    for (int s = 0; s < 4; ++s) {
        tmax[s] = -INFINITY;
#pragma unroll
        for (int r4 = 0; r4 < 4; ++r4) {
            int row = s * 16 + q * 4 + r4;
            float4 wm = *reinterpret_cast<const float4*>(&wavemin[row][0]);
            float v = fminf(fminf(wm.x, wm.y), fminf(wm.z, wm.w)) + margin_lds[row];
            thresh[s][r4] = v;
            tmax[s] = fmaxf(tmax[s], v);
        }
        tmax_all = fmaxf(tmax_all, tmax[s]);
    }

    // ================= pass 2: rescan own tiles, append candidates ===========
#pragma unroll 2
    for (int i = 0; i < TPW; ++i) {
        int t = tBase + i;
        short8 b0 = bfrag[(t * 2 + 0) * 64 + lane];
        short8 b1 = bfrag[(t * 2 + 1) * 64 + lane];
        float cn = cn_lds[t * 16 + m];
        f32x4 sc[4];
        float cmin = INFINITY;
#pragma unroll
        for (int s = 0; s < 4; ++s) {
            f32x4 acc = {0.f, 0.f, 0.f, 0.f};
            acc = __builtin_amdgcn_mfma_f32_16x16x32_bf16(af0[s], b0, acc, 0, 0, 0);
            acc = __builtin_amdgcn_mfma_f32_16x16x32_bf16(af1[s], b1, acc, 0, 0, 0);
#pragma unroll
            for (int r4 = 0; r4 < 4; ++r4) {
                sc[s][r4] = fmaf(-2.f, acc[r4], cn);
                cmin = fminf(cmin, sc[s][r4]);
            }
        }
        if (cmin < tmax_all) {            // rare: detailed per-row checks
#pragma unroll
            for (int s = 0; s < 4; ++s) {
                float smin = fminf(fminf(sc[s][0], sc[s][1]), fminf(sc[s][2], sc[s][3]));
                if (smin < tmax[s]) {
#pragma unroll
                    for (int r4 = 0; r4 < 4; ++r4) {
                        if (sc[s][r4] < thresh[s][r4]) {   // pass1==pass2 scores
                            int row = s * 16 + q * 4 + r4;
                            int slot = atomicAdd(&ccount[row], 1);
                            if (slot < MAXC) cand[row][slot] = t * 16 + m;
                        }
                    }
                }
            }
        }
    }
    __syncthreads();

    // ---- exact f64 resolve: tid<64 resolves row tid (argmin guaranteed in list)
    if (tid < TM) {
        int cnt = ccount[tid];
        int best;
        if (cnt == 1) {
            best = cand[tid][0];
        } else {
            const float* xp = inpt + (size_t)(rowBase + tid) * INPT_DIM + COL_OFF;
            double bestv = 1e300;
            best = 0x7fffffff;
            if (cnt <= MAXC) {
                for (int j = 0; j < cnt; ++j) {
                    int k = cand[tid][j];
                    double s = exact_score(centers + (size_t)k * DIM, xp, cnorm_d[k]);
                    if (s < bestv || (s == bestv && k < best)) { bestv = s; best = k; }
                }
            } else {  // overflow fallback: full exact scan (P ~ 0)
                for (int k = 0; k < NCENT; ++k) {
                    double s = exact_score(centers + (size_t)k * DIM, xp, cnorm_d[k]);
                    if (s < bestv) { bestv = s; best = k; }
                }
            }
        }
        out[rowBase + tid] = best;
    }
}

// ---------------------------------------------------------------------------
extern "C" void kernel_launch(void* const* d_in, const int* in_sizes, int n_in,
                              void* d_out, int out_size, void* d_ws, size_t ws_size,
                              hipStream_t stream) {
    const float* inpt     = (const float*)d_in[0];
    const float* centers1 = (const float*)d_in[2];   // centers0 (d_in[1]) unused
    int* out = (int*)d_out;

    char* ws = (char*)d_ws;
    double* cnorm_d = (double*)ws;
    float*  cnorm_f = (float*)(ws + 8192);
    int*    maxc_i  = (int*)(ws + 12288);
    unsigned short* cbf = (unsigned short*)(ws + 16384);

    prep_kernel<<<16, 256, 0, stream>>>(centers1, cnorm_d, cnorm_f, maxc_i, cbf);
    label_kernel<<<N_ROWS / TM, 256, 0, stream>>>(inpt, centers1, cnorm_d, cnorm_f,
                                                  maxc_i, cbf, out);
}

// Round 9
// 163.840 us; speedup vs baseline: 1.1233x; 1.1008x over previous
//
#include <hip/hip_runtime.h>
#include <math.h>

// labels = argmin_k ||c1_k||^2 - 2*x.c1_k, x = inpt[:,64:128] (131072x64),
// centers1 (1024x64). centers0 unused. Output int32 labels.
constexpr int N_ROWS   = 131072;
constexpr int INPT_DIM = 128;
constexpr int DIM      = 64;
constexpr int COL_OFF  = 64;
constexpr int NCENT    = 1024;

constexpr int TM    = 64;           // rows per block
constexpr int NTILE = NCENT / 16;   // 64 tiles of 16 centers
constexpr int TPW   = NTILE / 4;    // 16 tiles per wave
constexpr int MAXC  = 16;           // candidates/row (E~1.5 under final thresh)

typedef short short8 __attribute__((ext_vector_type(8)));
typedef float f32x4  __attribute__((ext_vector_type(4)));

// ws: [0,8192) f64 cnorm | [8192,12288) f32 cnorm | [12288,12292) maxC bits
//     [16384, 16384+131072) bf16 centers, MFMA-fragment-linear:
//     frag (tile t, khalf f) lane l: 8 bf16 at ((t*2+f)*64 + l)*8
//     = centers[t*16 + (l&15)][f*32 + (l>>4)*8 + j]   (B[n][k], m89 layout)

__device__ __forceinline__ unsigned short f2bf(float f) {
    unsigned u = __float_as_uint(f);
    u += 0x7fff + ((u >> 16) & 1);          // round-to-nearest-even
    return (unsigned short)(u >> 16);
}

__device__ __forceinline__ double exact_score(const float* __restrict__ c,
                                              const float* __restrict__ x, double cn) {
    double acc = 0.0;
#pragma unroll
    for (int d = 0; d < DIM; ++d)
        acc = fma((double)c[d], (double)x[d], acc);
    return fma(-2.0, acc, cn);
}

// ---------------------------------------------------------------------------
// Prep (unchanged): 4 threads/center, coalesced 64B quarter-rows.
// ---------------------------------------------------------------------------
__global__ __launch_bounds__(256) void prep_kernel(const float* __restrict__ centers,
                                                   double* __restrict__ cnorm_d,
                                                   float* __restrict__ cnorm_f,
                                                   int* __restrict__ maxc_i,
                                                   unsigned short* __restrict__ cbf) {
    int tid = blockIdx.x * 256 + threadIdx.x;   // 0..4095
    int k = tid >> 2, kq = tid & 3;
    const float* c = centers + (size_t)k * DIM + kq * 16;
    float cf[16];
    double sd = 0.0;
#pragma unroll
    for (int j = 0; j < 4; ++j) {
        float4 v = *reinterpret_cast<const float4*>(c + j * 4);
        cf[j * 4] = v.x; cf[j * 4 + 1] = v.y; cf[j * 4 + 2] = v.z; cf[j * 4 + 3] = v.w;
        sd = fma((double)v.x, (double)v.x, sd);
        sd = fma((double)v.y, (double)v.y, sd);
        sd = fma((double)v.z, (double)v.z, sd);
        sd = fma((double)v.w, (double)v.w, sd);
    }
    sd += __shfl_xor(sd, 1);
    sd += __shfl_xor(sd, 2);
    if (kq == 0) { cnorm_d[k] = sd; cnorm_f[k] = (float)sd; }

    int t = k >> 4, n = k & 15, f = kq >> 1;
#pragma unroll
    for (int h = 0; h < 2; ++h) {
        int qq = (kq & 1) * 2 + h;
        const float* s = cf + h * 8;
        uint4 w;
        w.x = (unsigned)f2bf(s[0]) | ((unsigned)f2bf(s[1]) << 16);
        w.y = (unsigned)f2bf(s[2]) | ((unsigned)f2bf(s[3]) << 16);
        w.z = (unsigned)f2bf(s[4]) | ((unsigned)f2bf(s[5]) << 16);
        w.w = (unsigned)f2bf(s[6]) | ((unsigned)f2bf(s[7]) << 16);
        *reinterpret_cast<uint4*>(cbf + ((size_t)((t * 2 + f) * 64 + qq * 16 + n)) * 8) = w;
    }
    float nm = sqrtf((float)sd);
#pragma unroll
    for (int mk = 1; mk < 64; mk <<= 1)
        nm = fmaxf(nm, __shfl_xor(nm, mk));
    if ((threadIdx.x & 63) == 0) atomicMax(maxc_i, __float_as_int(nm));  // poison<0 loses
}

// ---------------------------------------------------------------------------
// Main: 4 waves/block, 64 rows, centers split by wave. R7/R8 post-mortem:
// attributes could not stop the allocator from targeting the LDS-implied
// 8 waves/EU (64-VGPR cap -> 17 MB scratch spills). Fix is PHYSICAL: pad LDS
// to ~36 KB/block so max blocks/CU = 160KiB/36KB = 4 -> 4 waves/EU is the
// hardware-max occupancy -> regalloc budget 128 VGPRs -> ~90-VGPR working
// set (af-frags, rmin, thresh, B in flight) stays in registers.
// ---------------------------------------------------------------------------
__global__ __attribute__((amdgpu_waves_per_eu(2, 4))) __launch_bounds__(256)
void label_kernel(
        const float* __restrict__ inpt, const float* __restrict__ centers,
        const double* __restrict__ cnorm_d, const float* __restrict__ cnorm_f,
        const int* __restrict__ maxc_i, const unsigned short* __restrict__ cbf,
        int* __restrict__ out) {
    __shared__ unsigned short A_lds[TM][72];   // 144B rows: frag reads 2-way (free)
    __shared__ float cn_lds[NCENT];
    __shared__ float margin_lds[TM];
    __shared__ float nx2p[TM][4];
    __shared__ float wavemin[TM][4];           // [row][wave] -> float4 reads
    __shared__ int   cand[TM][MAXC];
    __shared__ int   ccount[TM];
    __shared__ char  lds_pad[16384];           // occupancy governor (see header)

    const int tid  = threadIdx.x;
    const int lane = tid & 63;
    const int w    = tid >> 6;                 // wave id 0..3
    const int rowBase = blockIdx.x * TM;

    // keep lds_pad live (prevents LDS-elimination of the pad)
    ((volatile char*)lds_pad)[tid] = 0;

    // ---- stage: thread (r,kq) converts 16 dims of row r; nx2 via partials
    {
        int r = tid >> 2, kq = tid & 3;
        const float* xp = inpt + (size_t)(rowBase + r) * INPT_DIM + COL_OFF + kq * 16;
        float ss = 0.f;
#pragma unroll
        for (int j = 0; j < 4; ++j) {
            float4 v = *reinterpret_cast<const float4*>(xp + j * 4);
            ss = fmaf(v.x, v.x, fmaf(v.y, v.y, fmaf(v.z, v.z, fmaf(v.w, v.w, ss))));
            unsigned u0 = (unsigned)f2bf(v.x) | ((unsigned)f2bf(v.y) << 16);
            unsigned u1 = (unsigned)f2bf(v.z) | ((unsigned)f2bf(v.w) << 16);
            *reinterpret_cast<unsigned*>(&A_lds[r][kq * 16 + j * 4])     = u0;
            *reinterpret_cast<unsigned*>(&A_lds[r][kq * 16 + j * 4 + 2]) = u1;
        }
        nx2p[r][kq] = ss;
        *reinterpret_cast<float4*>(&cn_lds[tid * 4]) =
            *reinterpret_cast<const float4*>(cnorm_f + tid * 4);
    }
    __syncthreads();
    if (tid < TM) {
        float nx2 = nx2p[tid][0] + nx2p[tid][1] + nx2p[tid][2] + nx2p[tid][3];
        // bf16 score err <= 2^-7|x||c| each way; formula unchanged since R3 (absmax=0)
        margin_lds[tid] = (1.5f / 64.f) * sqrtf(nx2) * __int_as_float(maxc_i[0]) + 1e-3f;
        ccount[tid] = 0;
    }
    __syncthreads();

    const int m = lane & 15, q = lane >> 4;
    short8 af0[4], af1[4];   // m89: A[m=lane&15][k=q*8+j]; 4 sets of 16 rows
#pragma unroll
    for (int s = 0; s < 4; ++s) {
        af0[s] = *reinterpret_cast<const short8*>(&A_lds[s * 16 + m][q * 8]);
        af1[s] = *reinterpret_cast<const short8*>(&A_lds[s * 16 + m][32 + q * 8]);
    }

    const short8* bfrag = reinterpret_cast<const short8*>(cbf);
    const int tBase = w * TPW;

    // ================= pass 1: running min over this wave's 256 centers ======
    float rmin[4][4];
#pragma unroll
    for (int s = 0; s < 4; ++s)
#pragma unroll
        for (int r4 = 0; r4 < 4; ++r4) rmin[s][r4] = INFINITY;

#pragma unroll 2
    for (int i = 0; i < TPW; ++i) {            // unroll 2: <=2 tiles of B in flight
        int t = tBase + i;
        short8 b0 = bfrag[(t * 2 + 0) * 64 + lane];
        short8 b1 = bfrag[(t * 2 + 1) * 64 + lane];
        float cn = cn_lds[t * 16 + m];
#pragma unroll
        for (int s = 0; s < 4; ++s) {
            f32x4 acc = {0.f, 0.f, 0.f, 0.f};
            acc = __builtin_amdgcn_mfma_f32_16x16x32_bf16(af0[s], b0, acc, 0, 0, 0);
            acc = __builtin_amdgcn_mfma_f32_16x16x32_bf16(af1[s], b1, acc, 0, 0, 0);
#pragma unroll
            for (int r4 = 0; r4 < 4; ++r4)   // D: col=m (center), row=q*4+r4
                rmin[s][r4] = fminf(rmin[s][r4], fmaf(-2.f, acc[r4], cn));
        }
    }

    // in-wave reduction over the 16-lane m-groups, then publish per-wave mins
#pragma unroll
    for (int s = 0; s < 4; ++s) {
#pragma unroll
        for (int r4 = 0; r4 < 4; ++r4) {
            float v = rmin[s][r4];
            v = fminf(v, __shfl_xor(v, 1));
            v = fminf(v, __shfl_xor(v, 2));
            v = fminf(v, __shfl_xor(v, 4));
            v = fminf(v, __shfl_xor(v, 8));
            if (m == 0) wavemin[s * 16 + q * 4 + r4][w] = v;
        }
    }
    __syncthreads();

    // global per-row thresholds = min over 4 waves + margin
    float thresh[4][4], tmax[4];
    float tmax_all = -INFINITY;
#pragma unroll
    for (int s = 0; s < 4; ++s) {
        tmax[s] = -INFINITY;
#pragma unroll
        for (int r4 = 0; r4 < 4; ++r4) {
            int row = s * 16 + q * 4 + r4;
            float4 wm = *reinterpret_cast<const float4*>(&wavemin[row][0]);
            float v = fminf(fminf(wm.x, wm.y), fminf(wm.z, wm.w)) + margin_lds[row];
            thresh[s][r4] = v;
            tmax[s] = fmaxf(tmax[s], v);
        }
        tmax_all = fmaxf(tmax_all, tmax[s]);
    }

    // ================= pass 2: rescan own tiles, append candidates ===========
#pragma unroll 2
    for (int i = 0; i < TPW; ++i) {
        int t = tBase + i;
        short8 b0 = bfrag[(t * 2 + 0) * 64 + lane];
        short8 b1 = bfrag[(t * 2 + 1) * 64 + lane];
        float cn = cn_lds[t * 16 + m];
        f32x4 sc[4];
        float cmin = INFINITY;
#pragma unroll
        for (int s = 0; s < 4; ++s) {
            f32x4 acc = {0.f, 0.f, 0.f, 0.f};
            acc = __builtin_amdgcn_mfma_f32_16x16x32_bf16(af0[s], b0, acc, 0, 0, 0);
            acc = __builtin_amdgcn_mfma_f32_16x16x32_bf16(af1[s], b1, acc, 0, 0, 0);
#pragma unroll
            for (int r4 = 0; r4 < 4; ++r4) {
                sc[s][r4] = fmaf(-2.f, acc[r4], cn);
                cmin = fminf(cmin, sc[s][r4]);
            }
        }
        if (cmin < tmax_all) {            // rare: detailed per-row checks
#pragma unroll
            for (int s = 0; s < 4; ++s) {
                float smin = fminf(fminf(sc[s][0], sc[s][1]), fminf(sc[s][2], sc[s][3]));
                if (smin < tmax[s]) {
#pragma unroll
                    for (int r4 = 0; r4 < 4; ++r4) {
                        if (sc[s][r4] < thresh[s][r4]) {   // pass1==pass2 scores
                            int row = s * 16 + q * 4 + r4;
                            int slot = atomicAdd(&ccount[row], 1);
                            if (slot < MAXC) cand[row][slot] = t * 16 + m;
                        }
                    }
                }
            }
        }
    }
    __syncthreads();

    // ---- exact f64 resolve: tid<64 resolves row tid (argmin guaranteed in list)
    if (tid < TM) {
        int cnt = ccount[tid];
        int best;
        if (cnt == 1) {
            best = cand[tid][0];
        } else {
            const float* xp = inpt + (size_t)(rowBase + tid) * INPT_DIM + COL_OFF;
            double bestv = 1e300;
            best = 0x7fffffff;
            if (cnt <= MAXC) {
                for (int j = 0; j < cnt; ++j) {
                    int k = cand[tid][j];
                    double s = exact_score(centers + (size_t)k * DIM, xp, cnorm_d[k]);
                    if (s < bestv || (s == bestv && k < best)) { bestv = s; best = k; }
                }
            } else {  // overflow fallback: full exact scan (P ~ 0)
                for (int k = 0; k < NCENT; ++k) {
                    double s = exact_score(centers + (size_t)k * DIM, xp, cnorm_d[k]);
                    if (s < bestv) { bestv = s; best = k; }
                }
            }
        }
        out[rowBase + tid] = best;
    }
}

// ---------------------------------------------------------------------------
extern "C" void kernel_launch(void* const* d_in, const int* in_sizes, int n_in,
                              void* d_out, int out_size, void* d_ws, size_t ws_size,
                              hipStream_t stream) {
    const float* inpt     = (const float*)d_in[0];
    const float* centers1 = (const float*)d_in[2];   // centers0 (d_in[1]) unused
    int* out = (int*)d_out;

    char* ws = (char*)d_ws;
    double* cnorm_d = (double*)ws;
    float*  cnorm_f = (float*)(ws + 8192);
    int*    maxc_i  = (int*)(ws + 12288);
    unsigned short* cbf = (unsigned short*)(ws + 16384);

    prep_kernel<<<16, 256, 0, stream>>>(centers1, cnorm_d, cnorm_f, maxc_i, cbf);
    label_kernel<<<N_ROWS / TM, 256, 0, stream>>>(inpt, centers1, cnorm_d, cnorm_f,
                                                  maxc_i, cbf, out);
}